// Round 7
// baseline (206.714 us; speedup 1.0000x reference)
//
#include <hip/hip_runtime.h>
#include <hip/hip_bf16.h>

// CCAM (fp32 in/out): x (16,1024,64,64), martx (4096,64).
// rows = B*C = 16384, N = 4096 spatial, KDIM = 64.
// energy[r][k] = sum_n x[r][n] * M[n][k]           (GEMM1, K=4096)
// att = softmax(alpha * (rowmax(energy) - energy))  (64-wide)
// out[r][n] = gamma * sum_k att[r][k]*M[n][k] + x[r][n]
//
// Round-7: round-6 kernel with ONE change — per-block staggered traversal
// order (phase-1 chunks start at blockIdx&15, phase-3 grps at blockIdx&7)
// to decorrelate the instantaneous HBM address pattern across the 512
// co-resident blocks (channel-camping hypothesis for the 2x BW gap).

using frag_ab = __attribute__((ext_vector_type(8))) short;   // 8 bf16 = 4 VGPR
using f32x4   = __attribute__((ext_vector_type(4))) float;   // MFMA C/D

#define MFMA16(a, b, c) __builtin_amdgcn_mfma_f32_16x16x32_bf16((a), (b), (c), 0, 0, 0)
#define AS1(p) ((const __attribute__((address_space(1))) void*)(p))
#define AS3(p) ((__attribute__((address_space(3))) void*)(p))
#define SBAR() __builtin_amdgcn_sched_barrier(0)

static __device__ __forceinline__ unsigned short f2bf_bits(float f) {
    __hip_bfloat16 h = __float2bfloat16(f);
    return *reinterpret_cast<const unsigned short*>(&h);
}
static __device__ __forceinline__ frag_ab load_frag(const __hip_bfloat16* p) {
    return *reinterpret_cast<const frag_ab*>(p);
}
static __device__ __forceinline__ frag_ab cvt2(float4 a, float4 b) {
    frag_ab r;
    r[0] = (short)f2bf_bits(a.x); r[1] = (short)f2bf_bits(a.y);
    r[2] = (short)f2bf_bits(a.z); r[3] = (short)f2bf_bits(a.w);
    r[4] = (short)f2bf_bits(b.x); r[5] = (short)f2bf_bits(b.y);
    r[6] = (short)f2bf_bits(b.z); r[7] = (short)f2bf_bits(b.w);
    return r;
}

// -------- kernel 0: build frag-linear B banks (unchanged, validated) --------
// MtF  (512 frags x 1 KB): frag f = slot*4+t, elem (lane,j) = M[32*slot+8g+j][16t+r15]
// MbfF (512 frags x 1 KB): frag f = nt*2+h,   elem (lane,j) = M[16nt+r15][32h+8g+j]
__global__ __launch_bounds__(256) void prep_frags(
        const float* __restrict__ M,
        __hip_bfloat16* __restrict__ MtF, __hip_bfloat16* __restrict__ MbfF) {
    const int w    = threadIdx.x >> 6;
    const int lane = threadIdx.x & 63;
    const int g    = lane >> 4;
    const int r15  = lane & 15;
    const int f    = blockIdx.x * 4 + w;    // 0..1023
    if (f < 512) {
        const int slot = f >> 2, t = f & 3;
        frag_ab fr;
#pragma unroll
        for (int j = 0; j < 8; ++j)
            fr[j] = (short)f2bf_bits(M[(size_t)(32 * slot + 8 * g + j) * 64 + 16 * t + r15]);
        *reinterpret_cast<frag_ab*>(MtF + ((size_t)f * 64 + lane) * 8) = fr;
    } else {
        const int f2 = f - 512;
        const float* src = M + (size_t)(16 * (f2 >> 1) + r15) * 64 + 32 * (f2 & 1) + 8 * g;
        float4 a = *reinterpret_cast<const float4*>(src);
        float4 b = *reinterpret_cast<const float4*>(src + 4);
        *reinterpret_cast<frag_ab*>(MbfF + ((size_t)f2 * 64 + lane) * 8) = cvt2(a, b);
    }
}

// -------- kernel 1: fused CCAM ----------------------------------------------
// LDS (69632 B):
//   phase 1: xbuf[3] at 0 / 16640 / 33280 (16 rows x 260 floats each)
//   phase 2: Ep[8][16][68] overlay at 0
//   phase 3: per-wave res double buffer at w*8704 (2 x 16 x 68 floats)
__global__ __launch_bounds__(512, 4) void ccam_main(
        const float* __restrict__ x,
        const __hip_bfloat16* __restrict__ MtF,
        const __hip_bfloat16* __restrict__ MbfF,
        const float* __restrict__ aphal,
        const float* __restrict__ gamma,
        float* __restrict__ out) {
    __shared__ __align__(16) char smem[69632];
    float* xb[3] = { (float*)smem, (float*)(smem + 16640), (float*)(smem + 33280) };
    float (*Ep)[16][68] = (float(*)[16][68])smem;

    const int tid  = threadIdx.x;
    const int w    = tid >> 6;        // wave 0..7
    const int lane = tid & 63;
    const int g    = lane >> 4;
    const int r15  = lane & 15;
    const int rowbase = blockIdx.x * 16;
    const int boff  = blockIdx.x & 15;   // phase-1 chunk stagger
    const int boff3 = blockIdx.x & 7;    // phase-3 grp stagger
    float* res0 = (float*)(smem + (size_t)w * 8704);   // 16 x 68 floats
    float* res1 = res0 + 1088;

    const float alpha = aphal[0];
    const float gam   = gamma[0];

    // ===== Phase 1: energy partials; chunk = 256 contraction cols, 16 chunks =====
    // wave w: stages rows 2w,2w+1 of each chunk; computes col-slot w (32 cols)
    // chunk visit order staggered per block: cidx(c) = (c + boff) & 15
    f32x4 acc0 = {0.f, 0.f, 0.f, 0.f};
    f32x4 acc1 = acc0, acc2 = acc0, acc3 = acc0;
    {
        frag_ab Bc0, Bc1, Bc2, Bc3, Bn0, Bn1, Bn2, Bn3;
        const int c0 = boff;
        const int c1 = (boff + 1) & 15;
        // prologue: DMA(cidx 0), B(cidx 0), DMA(cidx 1)  [order sets the counts]
#pragma unroll
        for (int i = 0; i < 2; ++i)
            __builtin_amdgcn_global_load_lds(
                AS1(x + (size_t)(rowbase + 2 * w + i) * 4096 + c0 * 256 + lane * 4),
                AS3(xb[0] + (2 * w + i) * 260), 16, 0, 0);
        {
            const __hip_bfloat16* bp = MtF + (((size_t)(8 * c0 + w) * 4) * 64 + lane) * 8;
            Bc0 = load_frag(bp);
            Bc1 = load_frag(bp + 512);
            Bc2 = load_frag(bp + 1024);
            Bc3 = load_frag(bp + 1536);
        }
#pragma unroll
        for (int i = 0; i < 2; ++i)
            __builtin_amdgcn_global_load_lds(
                AS1(x + (size_t)(rowbase + 2 * w + i) * 4096 + c1 * 256 + lane * 4),
                AS3(xb[1] + (2 * w + i) * 260), 16, 0, 0);
        SBAR();

#pragma unroll
        for (int c = 0; c < 16; ++c) {
            // 1. prefetch B(c+1) into Bn (4 x 1KB contiguous, L2-resident)
            if (c < 15) {
                const int cn = (c + 1 + boff) & 15;
                const __hip_bfloat16* bp = MtF + (((size_t)(8 * cn + w) * 4) * 64 + lane) * 8;
                Bn0 = load_frag(bp);
                Bn1 = load_frag(bp + 512);
                Bn2 = load_frag(bp + 1024);
                Bn3 = load_frag(bp + 1536);
            }
            // 2. DMA chunk c+2
            if (c < 14) {
                const int cf = (c + 2 + boff) & 15;
#pragma unroll
                for (int i = 0; i < 2; ++i)
                    __builtin_amdgcn_global_load_lds(
                        AS1(x + (size_t)(rowbase + 2 * w + i) * 4096 + cf * 256 + lane * 4),
                        AS3(xb[(c + 2) % 3] + (2 * w + i) * 260), 16, 0, 0);
            }
            SBAR();
            // 3. wait: DMA(c) + B(c) retired; DMA(c+1), B(c+1), DMA(c+2) in flight
            if (c <= 13)      asm volatile("s_waitcnt vmcnt(8)" ::: "memory");
            else if (c == 14) asm volatile("s_waitcnt vmcnt(6)" ::: "memory");
            else              asm volatile("s_waitcnt vmcnt(0)" ::: "memory");
            SBAR();
            __builtin_amdgcn_s_barrier();     // chunk c staged by all waves
            SBAR();
            // 4. compute chunk c, col-slot w
            {
                const float* ap = xb[c % 3] + r15 * 260 + 32 * w + 8 * g;
                float4 a0 = *reinterpret_cast<const float4*>(ap);
                float4 a1 = *reinterpret_cast<const float4*>(ap + 4);
                frag_ab a = cvt2(a0, a1);
                acc0 = MFMA16(a, Bc0, acc0);
                acc1 = MFMA16(a, Bc1, acc1);
                acc2 = MFMA16(a, Bc2, acc2);
                acc3 = MFMA16(a, Bc3, acc3);
            }
            // 5. release buffer (WAR for DMA(c+3) issued next iteration)
            asm volatile("s_waitcnt lgkmcnt(0)" ::: "memory");
            SBAR();
            __builtin_amdgcn_s_barrier();
            SBAR();
            Bc0 = Bn0; Bc1 = Bn1; Bc2 = Bn2; Bc3 = Bn3;
        }
    }
    __syncthreads();   // xbufs die; Ep region becomes live

    // ===== Phase 1b: partials -> Ep =====
    // D layout: col = r15 (kdim-in-16-tile), row = 4g+reg (channel)
#pragma unroll
    for (int r = 0; r < 4; ++r) {
        Ep[w][4 * g + r][ 0 + r15] = acc0[r];
        Ep[w][4 * g + r][16 + r15] = acc1[r];
        Ep[w][4 * g + r][32 + r15] = acc2[r];
        Ep[w][4 * g + r][48 + r15] = acc3[r];
    }
    __syncthreads();

    // ===== Phase 2: softmax (every wave redundantly; lands in A-frag layout) =====
    float e[16];
#pragma unroll
    for (int j = 0; j < 16; ++j) e[j] = 0.f;
#pragma unroll
    for (int p = 0; p < 8; ++p) {
        float4 lo  = *reinterpret_cast<const float4*>(&Ep[p][r15][8 * g]);
        float4 lo2 = *reinterpret_cast<const float4*>(&Ep[p][r15][8 * g + 4]);
        float4 hi  = *reinterpret_cast<const float4*>(&Ep[p][r15][32 + 8 * g]);
        float4 hi2 = *reinterpret_cast<const float4*>(&Ep[p][r15][32 + 8 * g + 4]);
        e[0] += lo.x;  e[1] += lo.y;  e[2]  += lo.z;  e[3]  += lo.w;
        e[4] += lo2.x; e[5] += lo2.y; e[6]  += lo2.z; e[7]  += lo2.w;
        e[8] += hi.x;  e[9] += hi.y;  e[10] += hi.z;  e[11] += hi.w;
        e[12] += hi2.x; e[13] += hi2.y; e[14] += hi2.z; e[15] += hi2.w;
    }
    float m = e[0];
#pragma unroll
    for (int j = 1; j < 16; ++j) m = fmaxf(m, e[j]);
    m = fmaxf(m, __shfl_xor(m, 16, 64));
    m = fmaxf(m, __shfl_xor(m, 32, 64));
#pragma unroll
    for (int j = 0; j < 16; ++j) e[j] = alpha * (m - e[j]);
    float vm = e[0];
#pragma unroll
    for (int j = 1; j < 16; ++j) vm = fmaxf(vm, e[j]);
    vm = fmaxf(vm, __shfl_xor(vm, 16, 64));
    vm = fmaxf(vm, __shfl_xor(vm, 32, 64));
    float s = 0.f;
#pragma unroll
    for (int j = 0; j < 16; ++j) { e[j] = __expf(e[j] - vm); s += e[j]; }
    s += __shfl_xor(s, 16, 64);
    s += __shfl_xor(s, 32, 64);
    const float sc = gam / s;                 // fold gamma into attention
    frag_ab A0, A1;   // row = r15 (channel), k = 8g+j (A0) / 32+8g+j (A1)
#pragma unroll
    for (int j = 0; j < 8; ++j) {
        A0[j] = (short)f2bf_bits(e[j] * sc);
        A1[j] = (short)f2bf_bits(e[8 + j] * sc);
    }
    __syncthreads();   // Ep dead; res region becomes live

    // ===== Phase 3: out = (gam*att) @ M^T + x ; wave-private, no barriers =====
    // wave w covers n in [512w, 512w+512): 8 grps of 64 cols, visit order
    // staggered per block: gidx(i) = (i + boff3) & 7 ; res double-buffered
    const int nb0 = w * 512;
    // prologue: residual DMA gidx(0) -> res0 (16 rows x 256 B)
#pragma unroll
    for (int i = 0; i < 16; ++i)
        __builtin_amdgcn_global_load_lds(
            AS1(x + (size_t)(rowbase + i) * 4096 + nb0 + boff3 * 64 + lane),
            AS3(res0 + i * 68), 4, 0, 0);
    SBAR();
#pragma unroll
    for (int grp = 0; grp < 8; ++grp) {
        const int gi    = (grp + boff3) & 7;
        const int nbase = nb0 + gi * 64;
        const int nt0   = 32 * w + 4 * gi;
        float* rcur = (grp & 1) ? res1 : res0;
        float* rnxt = (grp & 1) ? res0 : res1;
        // 1. B(grp) first (so the B-wait leaves DMA(grp+1) in flight)
        const __hip_bfloat16* bb = MbfF + ((size_t)nt0 * 2 * 64 + lane) * 8;
        frag_ab b00 = load_frag(bb);
        frag_ab b01 = load_frag(bb + 512);
        frag_ab b10 = load_frag(bb + 1024);
        frag_ab b11 = load_frag(bb + 1536);
        frag_ab b20 = load_frag(bb + 2048);
        frag_ab b21 = load_frag(bb + 2560);
        frag_ab b30 = load_frag(bb + 3072);
        frag_ab b31 = load_frag(bb + 3584);
        SBAR();
        // 2. DMA grp+1 residual into the other buffer
        if (grp < 7) {
            const int gn = (grp + 1 + boff3) & 7;
#pragma unroll
            for (int i = 0; i < 16; ++i)
                __builtin_amdgcn_global_load_lds(
                    AS1(x + (size_t)(rowbase + i) * 4096 + nb0 + gn * 64 + lane),
                    AS3(rnxt + i * 68), 4, 0, 0);
        }
        SBAR();
        // 3. wait: DMA(grp) + B(grp) retired; DMA(grp+1) stays in flight
        if (grp < 7) asm volatile("s_waitcnt vmcnt(16)" ::: "memory");
        else         asm volatile("s_waitcnt vmcnt(0)" ::: "memory");
        SBAR();
        // 4. MFMA (B already waited) + residual reads from rcur
        f32x4 d0 = {0.f, 0.f, 0.f, 0.f};
        f32x4 d1 = d0, d2 = d0, d3 = d0;
        d0 = MFMA16(A0, b00, d0); d0 = MFMA16(A1, b01, d0);
        d1 = MFMA16(A0, b10, d1); d1 = MFMA16(A1, b11, d1);
        d2 = MFMA16(A0, b20, d2); d2 = MFMA16(A1, b21, d2);
        d3 = MFMA16(A0, b30, d3); d3 = MFMA16(A1, b31, d3);
        float rv[16];
#pragma unroll
        for (int r = 0; r < 4; ++r) {
            const float* rr = rcur + (4 * g + r) * 68 + r15;
            rv[r * 4 + 0] = rr[ 0];
            rv[r * 4 + 1] = rr[16];
            rv[r * 4 + 2] = rr[32];
            rv[r * 4 + 3] = rr[48];
        }
        asm volatile("s_waitcnt lgkmcnt(0)" ::: "memory");  // rcur reads done (WAR)
        SBAR();
        // 5. store out
#pragma unroll
        for (int r = 0; r < 4; ++r) {
            float* op = out + (size_t)(rowbase + 4 * g + r) * 4096 + nbase + r15;
            op[ 0] = d0[r] + rv[r * 4 + 0];
            op[16] = d1[r] + rv[r * 4 + 1];
            op[32] = d2[r] + rv[r * 4 + 2];
            op[48] = d3[r] + rv[r * 4 + 3];
        }
    }
}

extern "C" void kernel_launch(void* const* d_in, const int* in_sizes, int n_in,
                              void* d_out, int out_size, void* d_ws, size_t ws_size,
                              hipStream_t stream) {
    const float* x     = (const float*)d_in[0];
    const float* M     = (const float*)d_in[1];
    const float* aphal = (const float*)d_in[2];
    const float* gamma = (const float*)d_in[3];
    __hip_bfloat16* MtF  = (__hip_bfloat16*)d_ws;                  // 512 KB
    __hip_bfloat16* MbfF = (__hip_bfloat16*)d_ws + 64 * 4096;      // 512 KB

    hipLaunchKernelGGL(prep_frags, dim3(256), dim3(256), 0, stream, M, MtF, MbfF);
    hipLaunchKernelGGL(ccam_main, dim3(1024), dim3(512), 0, stream,
                       x, MtF, MbfF, aphal, gamma, (float*)d_out);
}

// Round 8
// 203.348 us; speedup vs baseline: 1.0166x; 1.0166x over previous
//
#include <hip/hip_runtime.h>
#include <hip/hip_bf16.h>

// CCAM (fp32 in/out): x (16,1024,64,64), martx (4096,64).
// rows = B*C = 16384, N = 4096 spatial, KDIM = 64.
// energy[r][k] = sum_n x[r][n] * M[n][k]           (GEMM1, K=4096)
// att = softmax(alpha * (rowmax(energy) - energy))  (64-wide)
// out[r][n] = gamma * sum_k att[r][k]*M[n][k] + x[r][n]
//
// Round-8: revert round-7 stagger (refuted, regressed). Split the round-6
// kernel at the att seam into two kernels:
//   ccam_energy: phase 1+2 (proven round-6 schedule), 49.9 KB LDS ->
//                3 blocks/CU; stores gamma-scaled att A-frags (2 MB) to ws.
//   ccam_out:    barrier-free streaming GEMM2+residual, 4 waves, wave-private
//                LDS transpose, fully-coalesced 256B x loads / out stores.

using frag_ab = __attribute__((ext_vector_type(8))) short;   // 8 bf16 = 4 VGPR
using f32x4   = __attribute__((ext_vector_type(4))) float;   // MFMA C/D

#define MFMA16(a, b, c) __builtin_amdgcn_mfma_f32_16x16x32_bf16((a), (b), (c), 0, 0, 0)
#define AS1(p) ((const __attribute__((address_space(1))) void*)(p))
#define AS3(p) ((__attribute__((address_space(3))) void*)(p))
#define SBAR() __builtin_amdgcn_sched_barrier(0)

static __device__ __forceinline__ unsigned short f2bf_bits(float f) {
    __hip_bfloat16 h = __float2bfloat16(f);
    return *reinterpret_cast<const unsigned short*>(&h);
}
static __device__ __forceinline__ frag_ab load_frag(const __hip_bfloat16* p) {
    return *reinterpret_cast<const frag_ab*>(p);
}
static __device__ __forceinline__ frag_ab cvt2(float4 a, float4 b) {
    frag_ab r;
    r[0] = (short)f2bf_bits(a.x); r[1] = (short)f2bf_bits(a.y);
    r[2] = (short)f2bf_bits(a.z); r[3] = (short)f2bf_bits(a.w);
    r[4] = (short)f2bf_bits(b.x); r[5] = (short)f2bf_bits(b.y);
    r[6] = (short)f2bf_bits(b.z); r[7] = (short)f2bf_bits(b.w);
    return r;
}

// -------- kernel 0: build frag-linear B banks (unchanged, validated) --------
// MtF  (512 frags x 1 KB): frag f = slot*4+t, elem (lane,j) = M[32*slot+8g+j][16t+r15]
// MbfF (512 frags x 1 KB): frag f = nt*2+h,   elem (lane,j) = M[16nt+r15][32h+8g+j]
__global__ __launch_bounds__(256) void prep_frags(
        const float* __restrict__ M,
        __hip_bfloat16* __restrict__ MtF, __hip_bfloat16* __restrict__ MbfF) {
    const int w    = threadIdx.x >> 6;
    const int lane = threadIdx.x & 63;
    const int g    = lane >> 4;
    const int r15  = lane & 15;
    const int f    = blockIdx.x * 4 + w;    // 0..1023
    if (f < 512) {
        const int slot = f >> 2, t = f & 3;
        frag_ab fr;
#pragma unroll
        for (int j = 0; j < 8; ++j)
            fr[j] = (short)f2bf_bits(M[(size_t)(32 * slot + 8 * g + j) * 64 + 16 * t + r15]);
        *reinterpret_cast<frag_ab*>(MtF + ((size_t)f * 64 + lane) * 8) = fr;
    } else {
        const int f2 = f - 512;
        const float* src = M + (size_t)(16 * (f2 >> 1) + r15) * 64 + 32 * (f2 & 1) + 8 * g;
        float4 a = *reinterpret_cast<const float4*>(src);
        float4 b = *reinterpret_cast<const float4*>(src + 4);
        *reinterpret_cast<frag_ab*>(MbfF + ((size_t)f2 * 64 + lane) * 8) = cvt2(a, b);
    }
}

// -------- kernel 1: energy GEMM + softmax -> att A-frags ---------------------
// LDS (49920 B): xbuf[3] at 0/16640/33280 (16 rows x 260 floats each);
//                Ep[8][16][68] overlays [0,34816) after the K loop.
__global__ __launch_bounds__(512, 6) void ccam_energy(
        const float* __restrict__ x,
        const __hip_bfloat16* __restrict__ MtF,
        const float* __restrict__ aphal,
        const float* __restrict__ gamma,
        __hip_bfloat16* __restrict__ att) {
    __shared__ __align__(16) char smem[49920];
    float* xb[3] = { (float*)smem, (float*)(smem + 16640), (float*)(smem + 33280) };
    float (*Ep)[16][68] = (float(*)[16][68])smem;

    const int tid  = threadIdx.x;
    const int w    = tid >> 6;        // wave 0..7
    const int lane = tid & 63;
    const int g    = lane >> 4;
    const int r15  = lane & 15;
    const int rowbase = blockIdx.x * 16;

    const float alpha = aphal[0];
    const float gam   = gamma[0];

    // ===== Phase 1: chunk = 256 contraction cols, 16 chunks (round-6 schedule) =====
    f32x4 acc0 = {0.f, 0.f, 0.f, 0.f};
    f32x4 acc1 = acc0, acc2 = acc0, acc3 = acc0;
    {
        frag_ab Bc0, Bc1, Bc2, Bc3, Bn0, Bn1, Bn2, Bn3;
        // prologue: DMA(0), B(0), DMA(1)   [this exact order sets the counts]
#pragma unroll
        for (int i = 0; i < 2; ++i)
            __builtin_amdgcn_global_load_lds(
                AS1(x + (size_t)(rowbase + 2 * w + i) * 4096 + lane * 4),
                AS3(xb[0] + (2 * w + i) * 260), 16, 0, 0);
        {
            const __hip_bfloat16* bp = MtF + (((size_t)w * 4) * 64 + lane) * 8;
            Bc0 = load_frag(bp);
            Bc1 = load_frag(bp + 512);
            Bc2 = load_frag(bp + 1024);
            Bc3 = load_frag(bp + 1536);
        }
#pragma unroll
        for (int i = 0; i < 2; ++i)
            __builtin_amdgcn_global_load_lds(
                AS1(x + (size_t)(rowbase + 2 * w + i) * 4096 + 256 + lane * 4),
                AS3(xb[1] + (2 * w + i) * 260), 16, 0, 0);
        SBAR();

#pragma unroll
        for (int c = 0; c < 16; ++c) {
            // 1. prefetch B(c+1)
            if (c < 15) {
                const __hip_bfloat16* bp = MtF + (((size_t)(8 * (c + 1) + w) * 4) * 64 + lane) * 8;
                Bn0 = load_frag(bp);
                Bn1 = load_frag(bp + 512);
                Bn2 = load_frag(bp + 1024);
                Bn3 = load_frag(bp + 1536);
            }
            // 2. DMA chunk c+2
            if (c < 14) {
#pragma unroll
                for (int i = 0; i < 2; ++i)
                    __builtin_amdgcn_global_load_lds(
                        AS1(x + (size_t)(rowbase + 2 * w + i) * 4096 + (c + 2) * 256 + lane * 4),
                        AS3(xb[(c + 2) % 3] + (2 * w + i) * 260), 16, 0, 0);
            }
            SBAR();
            // 3. wait: DMA(c)+B(c) retired; DMA(c+1), B(c+1), DMA(c+2) in flight
            if (c <= 13)      asm volatile("s_waitcnt vmcnt(8)" ::: "memory");
            else if (c == 14) asm volatile("s_waitcnt vmcnt(6)" ::: "memory");
            else              asm volatile("s_waitcnt vmcnt(0)" ::: "memory");
            SBAR();
            __builtin_amdgcn_s_barrier();     // chunk c staged by all waves
            SBAR();
            // 4. compute chunk c, col-slot w
            {
                const float* ap = xb[c % 3] + r15 * 260 + 32 * w + 8 * g;
                float4 a0 = *reinterpret_cast<const float4*>(ap);
                float4 a1 = *reinterpret_cast<const float4*>(ap + 4);
                frag_ab a = cvt2(a0, a1);
                acc0 = MFMA16(a, Bc0, acc0);
                acc1 = MFMA16(a, Bc1, acc1);
                acc2 = MFMA16(a, Bc2, acc2);
                acc3 = MFMA16(a, Bc3, acc3);
            }
            // 5. release buffer (WAR for DMA(c+3))
            asm volatile("s_waitcnt lgkmcnt(0)" ::: "memory");
            SBAR();
            __builtin_amdgcn_s_barrier();
            SBAR();
            Bc0 = Bn0; Bc1 = Bn1; Bc2 = Bn2; Bc3 = Bn3;
        }
    }
    __syncthreads();   // xbufs die; Ep region becomes live

    // ===== partials -> Ep =====
    // D layout: col = r15 (kdim-in-16-tile), row = 4g+reg (channel)
#pragma unroll
    for (int r = 0; r < 4; ++r) {
        Ep[w][4 * g + r][ 0 + r15] = acc0[r];
        Ep[w][4 * g + r][16 + r15] = acc1[r];
        Ep[w][4 * g + r][32 + r15] = acc2[r];
        Ep[w][4 * g + r][48 + r15] = acc3[r];
    }
    __syncthreads();

    // ===== Phase 2: softmax (every wave redundantly; lands in A-frag layout) =====
    float e[16];
#pragma unroll
    for (int j = 0; j < 16; ++j) e[j] = 0.f;
#pragma unroll
    for (int p = 0; p < 8; ++p) {
        float4 lo  = *reinterpret_cast<const float4*>(&Ep[p][r15][8 * g]);
        float4 lo2 = *reinterpret_cast<const float4*>(&Ep[p][r15][8 * g + 4]);
        float4 hi  = *reinterpret_cast<const float4*>(&Ep[p][r15][32 + 8 * g]);
        float4 hi2 = *reinterpret_cast<const float4*>(&Ep[p][r15][32 + 8 * g + 4]);
        e[0] += lo.x;  e[1] += lo.y;  e[2]  += lo.z;  e[3]  += lo.w;
        e[4] += lo2.x; e[5] += lo2.y; e[6]  += lo2.z; e[7]  += lo2.w;
        e[8] += hi.x;  e[9] += hi.y;  e[10] += hi.z;  e[11] += hi.w;
        e[12] += hi2.x; e[13] += hi2.y; e[14] += hi2.z; e[15] += hi2.w;
    }
    float m = e[0];
#pragma unroll
    for (int j = 1; j < 16; ++j) m = fmaxf(m, e[j]);
    m = fmaxf(m, __shfl_xor(m, 16, 64));
    m = fmaxf(m, __shfl_xor(m, 32, 64));
#pragma unroll
    for (int j = 0; j < 16; ++j) e[j] = alpha * (m - e[j]);
    float vm = e[0];
#pragma unroll
    for (int j = 1; j < 16; ++j) vm = fmaxf(vm, e[j]);
    vm = fmaxf(vm, __shfl_xor(vm, 16, 64));
    vm = fmaxf(vm, __shfl_xor(vm, 32, 64));
    float s = 0.f;
#pragma unroll
    for (int j = 0; j < 16; ++j) { e[j] = __expf(e[j] - vm); s += e[j]; }
    s += __shfl_xor(s, 16, 64);
    s += __shfl_xor(s, 32, 64);
    const float sc = gam / s;                 // fold gamma into attention
    // A-frag values: row = r15 (channel), k = 8g+j / 32+8g+j
    if (w == 0) {
        frag_ab A0, A1;
#pragma unroll
        for (int j = 0; j < 8; ++j) {
            A0[j] = (short)f2bf_bits(e[j] * sc);
            A1[j] = (short)f2bf_bits(e[8 + j] * sc);
        }
        __hip_bfloat16* ap = att + (size_t)blockIdx.x * 1024;
        *reinterpret_cast<frag_ab*>(ap + lane * 8)       = A0;
        *reinterpret_cast<frag_ab*>(ap + 512 + lane * 8) = A1;
    }
}

// -------- kernel 2: out = (gam*att) @ M^T + x  (streaming, barrier-free) ----
// 256 threads / 4 waves; wave w covers n in [1024w, 1024w+1024), 16 grps of 64.
__global__ __launch_bounds__(256, 4) void ccam_out(
        const float* __restrict__ x,
        const __hip_bfloat16* __restrict__ MbfF,
        const __hip_bfloat16* __restrict__ att,
        float* __restrict__ out) {
    __shared__ __align__(16) float outS[4][16][66];   // pad 66 -> <=2-way banks

    const int tid  = threadIdx.x;
    const int w    = tid >> 6;        // wave 0..3
    const int lane = tid & 63;
    const int g    = lane >> 4;
    const int r15  = lane & 15;
    const int rowbase = blockIdx.x * 16;

    // att A-frags (gamma folded in by ccam_energy)
    const __hip_bfloat16* ap = att + (size_t)blockIdx.x * 1024;
    frag_ab A0 = *reinterpret_cast<const frag_ab*>(ap + lane * 8);
    frag_ab A1 = *reinterpret_cast<const frag_ab*>(ap + 512 + lane * 8);

    const int nb0 = w * 1024;
#pragma unroll 1
    for (int grp = 0; grp < 16; ++grp) {
        const int nbase = nb0 + grp * 64;
        // 1. residual row loads FIRST (256B contiguous each; latency hides under B+MFMA)
        float xv[16];
#pragma unroll
        for (int r = 0; r < 16; ++r)
            xv[r] = x[(size_t)(rowbase + r) * 4096 + nbase + lane];
        // 2. B-frags (L2-resident; issued after xv -> B-wait implies xv done)
        const int nt0 = 64 * w + 4 * grp;
        const __hip_bfloat16* bb = MbfF + ((size_t)nt0 * 2 * 64 + lane) * 8;
        frag_ab b00 = load_frag(bb);
        frag_ab b01 = load_frag(bb + 512);
        frag_ab b10 = load_frag(bb + 1024);
        frag_ab b11 = load_frag(bb + 1536);
        frag_ab b20 = load_frag(bb + 2048);
        frag_ab b21 = load_frag(bb + 2560);
        frag_ab b30 = load_frag(bb + 3072);
        frag_ab b31 = load_frag(bb + 3584);
        // 3. MFMA
        f32x4 d0 = {0.f, 0.f, 0.f, 0.f};
        f32x4 d1 = d0, d2 = d0, d3 = d0;
        d0 = MFMA16(A0, b00, d0); d0 = MFMA16(A1, b01, d0);
        d1 = MFMA16(A0, b10, d1); d1 = MFMA16(A1, b11, d1);
        d2 = MFMA16(A0, b20, d2); d2 = MFMA16(A1, b21, d2);
        d3 = MFMA16(A0, b30, d3); d3 = MFMA16(A1, b31, d3);
        // 4. transpose D through wave-private LDS
        //    D layout: d_t[r] -> row 4g+r (channel), col 16t+r15
#pragma unroll
        for (int r = 0; r < 4; ++r) {
            outS[w][4 * g + r][ 0 + r15] = d0[r];
            outS[w][4 * g + r][16 + r15] = d1[r];
            outS[w][4 * g + r][32 + r15] = d2[r];
            outS[w][4 * g + r][48 + r15] = d3[r];
        }
        asm volatile("s_waitcnt lgkmcnt(0)" ::: "memory");   // wave-private RAW
        SBAR();
        // 5. row-broadcast epilogue: 256B contiguous store per row
#pragma unroll
        for (int r = 0; r < 16; ++r) {
            float v = outS[w][r][lane] + xv[r];
            out[(size_t)(rowbase + r) * 4096 + nbase + lane] = v;
        }
        // same-wave DS ordering guarantees next grp's ds_writes can't pass
        // this grp's ds_reads; no extra fence needed.
    }
}

extern "C" void kernel_launch(void* const* d_in, const int* in_sizes, int n_in,
                              void* d_out, int out_size, void* d_ws, size_t ws_size,
                              hipStream_t stream) {
    const float* x     = (const float*)d_in[0];
    const float* M     = (const float*)d_in[1];
    const float* aphal = (const float*)d_in[2];
    const float* gamma = (const float*)d_in[3];
    __hip_bfloat16* MtF  = (__hip_bfloat16*)d_ws;                    // 512 KB
    __hip_bfloat16* MbfF = (__hip_bfloat16*)d_ws + 64 * 4096;        // 512 KB
    __hip_bfloat16* att  = (__hip_bfloat16*)d_ws + 2 * 64 * 4096;    // 2 MB

    hipLaunchKernelGGL(prep_frags, dim3(256), dim3(256), 0, stream, M, MtF, MbfF);
    hipLaunchKernelGGL(ccam_energy, dim3(1024), dim3(512), 0, stream,
                       x, MtF, aphal, gamma, att);
    hipLaunchKernelGGL(ccam_out, dim3(1024), dim3(256), 0, stream,
                       x, MbfF, att, (float*)d_out);
}

// Round 9
// 202.636 us; speedup vs baseline: 1.0201x; 1.0035x over previous
//
#include <hip/hip_runtime.h>
#include <hip/hip_bf16.h>

// CCAM (fp32 in/out): x (16,1024,64,64), martx (4096,64).
// rows = B*C = 16384, N = 4096 spatial, KDIM = 64.
// energy[r][k] = sum_n x[r][n] * M[n][k]           (GEMM1, K=4096)
// att = softmax(alpha * (rowmax(energy) - energy))  (64-wide)
// out[r][n] = gamma * sum_k att[r][k]*M[n][k] + x[r][n]
//
// Round-9: ZERO-SYNC design. One wave owns 16 rows end-to-end:
//   phase 1: full-K energy GEMM, wave-private LDS dbuf fed by global_load_lds,
//            counted vmcnt(24) self-pacing, no barriers anywhere
//   phase 2: per-wave softmax (kdim is lane-resident), wave-private transpose
//   phase 3: wave-private streaming GEMM2 + residual, 2-grp reg double buffer
// Grid = 1024 x 64 threads (1 wave/block, 4 waves/CU). Low occupancy by
// design; MLP comes from per-wave in-flight DMA/load queues, not TLP.

using frag_ab = __attribute__((ext_vector_type(8))) short;   // 8 bf16 = 4 VGPR
using f32x4   = __attribute__((ext_vector_type(4))) float;   // MFMA C/D

#define MFMA16(a, b, c) __builtin_amdgcn_mfma_f32_16x16x32_bf16((a), (b), (c), 0, 0, 0)
#define AS1(p) ((const __attribute__((address_space(1))) void*)(p))
#define AS3(p) ((__attribute__((address_space(3))) void*)(p))
#define SBAR() __builtin_amdgcn_sched_barrier(0)

static __device__ __forceinline__ unsigned short f2bf_bits(float f) {
    __hip_bfloat16 h = __float2bfloat16(f);
    return *reinterpret_cast<const unsigned short*>(&h);
}
static __device__ __forceinline__ frag_ab load_frag(const __hip_bfloat16* p) {
    return *reinterpret_cast<const frag_ab*>(p);
}
static __device__ __forceinline__ frag_ab cvt2(float4 a, float4 b) {
    frag_ab r;
    r[0] = (short)f2bf_bits(a.x); r[1] = (short)f2bf_bits(a.y);
    r[2] = (short)f2bf_bits(a.z); r[3] = (short)f2bf_bits(a.w);
    r[4] = (short)f2bf_bits(b.x); r[5] = (short)f2bf_bits(b.y);
    r[6] = (short)f2bf_bits(b.z); r[7] = (short)f2bf_bits(b.w);
    return r;
}

// -------- kernel 0: build frag-linear B banks (unchanged, validated) --------
// MtF  (512 frags x 1 KB): frag f = slot*4+t, elem (lane,j) = M[32*slot+8g+j][16t+r15]
// MbfF (512 frags x 1 KB): frag f = nt*2+h,   elem (lane,j) = M[16nt+r15][32h+8g+j]
__global__ __launch_bounds__(256) void prep_frags(
        const float* __restrict__ M,
        __hip_bfloat16* __restrict__ MtF, __hip_bfloat16* __restrict__ MbfF) {
    const int w    = threadIdx.x >> 6;
    const int lane = threadIdx.x & 63;
    const int g    = lane >> 4;
    const int r15  = lane & 15;
    const int f    = blockIdx.x * 4 + w;    // 0..1023
    if (f < 512) {
        const int slot = f >> 2, t = f & 3;
        frag_ab fr;
#pragma unroll
        for (int j = 0; j < 8; ++j)
            fr[j] = (short)f2bf_bits(M[(size_t)(32 * slot + 8 * g + j) * 64 + 16 * t + r15]);
        *reinterpret_cast<frag_ab*>(MtF + ((size_t)f * 64 + lane) * 8) = fr;
    } else {
        const int f2 = f - 512;
        const float* src = M + (size_t)(16 * (f2 >> 1) + r15) * 64 + 32 * (f2 & 1) + 8 * g;
        float4 a = *reinterpret_cast<const float4*>(src);
        float4 b = *reinterpret_cast<const float4*>(src + 4);
        *reinterpret_cast<frag_ab*>(MbfF + ((size_t)f2 * 64 + lane) * 8) = cvt2(a, b);
    }
}

// -------- kernel 1: fused CCAM, one wave per 16 rows, zero barriers ---------
// LDS 16.4 KB: buf0 [0,8192), buf1 [8192,16384) (16 rows x 128 f32 each);
//              Ep/outS (16 x 68 f32 = 4352 B) overlays buf0 between phases.
__global__ __launch_bounds__(64, 1) void ccam_fused(
        const float* __restrict__ x,
        const __hip_bfloat16* __restrict__ MtF,
        const __hip_bfloat16* __restrict__ MbfF,
        const float* __restrict__ aphal,
        const float* __restrict__ gamma,
        float* __restrict__ out) {
    __shared__ __align__(16) char smem[16384];
    float* buf0 = (float*)smem;
    float* buf1 = (float*)(smem + 8192);
    float* Ep   = (float*)smem;            // 16 x 68 overlay (phase 2 / outS)

    const int lane = threadIdx.x;          // 0..63
    const int g    = lane >> 4;
    const int r15  = lane & 15;
    const int hi   = lane >> 5;            // row-pair half for DMA
    const int c32  = lane & 31;
    const int row0 = blockIdx.x * 16;

    const float alpha = aphal[0];
    const float gam   = gamma[0];

    // ===== Phase 1: energy, full K per wave; chunks of 128 cols, 32 chunks =====
    f32x4 acc0 = {0.f, 0.f, 0.f, 0.f};
    f32x4 acc1 = acc0, acc2 = acc0, acc3 = acc0;
    frag_ab BA[4][4], BB[4][4];

    // stage chunk c into dst: 8 DMA instrs, each moves a 2-row pair (1 KB)
    auto dma_chunk = [&](int c, float* dst) {
#pragma unroll
        for (int p = 0; p < 8; ++p) {
            const float* gp = x + (size_t)(row0 + 2 * p + hi) * 4096 + c * 128 + c32 * 4;
            __builtin_amdgcn_global_load_lds(AS1(gp), AS3(dst + p * 256), 16, 0, 0);
        }
    };
    auto loadB1 = [&](int c, frag_ab (&B)[4][4]) {
#pragma unroll
        for (int ks = 0; ks < 4; ++ks)
#pragma unroll
            for (int t = 0; t < 4; ++t)
                B[ks][t] = load_frag(MtF + (((size_t)(4 * c + ks) * 4 + t) * 64 + lane) * 8);
    };
    auto comp1 = [&](const float* buf, frag_ab (&B)[4][4]) {
#pragma unroll
        for (int ks = 0; ks < 4; ++ks) {
            const float* ap = buf + r15 * 128 + 32 * ks + 8 * g;
            float4 a0 = *reinterpret_cast<const float4*>(ap);
            float4 a1 = *reinterpret_cast<const float4*>(ap + 4);
            frag_ab a = cvt2(a0, a1);
            acc0 = MFMA16(a, B[ks][0], acc0);
            acc1 = MFMA16(a, B[ks][1], acc1);
            acc2 = MFMA16(a, B[ks][2], acc2);
            acc3 = MFMA16(a, B[ks][3], acc3);
        }
    };

    // prologue: DMA(0), B(0), DMA(1), B(1)   -> 48 outstanding
    dma_chunk(0, buf0); loadB1(0, BA);
    dma_chunk(1, buf1); loadB1(1, BB);
    SBAR();
#pragma unroll
    for (int i = 0; i < 16; ++i) {
        // ---- even chunk e = 2i (buf0, BA) ----
        asm volatile("s_waitcnt vmcnt(24)" ::: "memory");   // DMA(e)+B(e) done
        SBAR();
        comp1(buf0, BA);
        asm volatile("s_waitcnt lgkmcnt(0)" ::: "memory");  // buf0 reads retired
        SBAR();
        if (i < 15) { dma_chunk(2 * i + 2, buf0); loadB1(2 * i + 2, BA); }
        SBAR();
        // ---- odd chunk o = 2i+1 (buf1, BB) ----
        if (i < 15) asm volatile("s_waitcnt vmcnt(24)" ::: "memory");
        else        asm volatile("s_waitcnt vmcnt(0)"  ::: "memory");
        SBAR();
        comp1(buf1, BB);
        asm volatile("s_waitcnt lgkmcnt(0)" ::: "memory");
        SBAR();
        if (i < 15) { dma_chunk(2 * i + 3, buf1); loadB1(2 * i + 3, BB); }
        SBAR();
    }

    // ===== Phase 2: per-wave softmax; D layout: row 4g+r, kdim 16t+r15 =====
#pragma unroll
    for (int r = 0; r < 4; ++r) {
        float e0 = acc0[r], e1 = acc1[r], e2 = acc2[r], e3 = acc3[r];
        float mx = fmaxf(fmaxf(e0, e1), fmaxf(e2, e3));
        mx = fmaxf(mx, __shfl_xor(mx, 1, 64));
        mx = fmaxf(mx, __shfl_xor(mx, 2, 64));
        mx = fmaxf(mx, __shfl_xor(mx, 4, 64));
        mx = fmaxf(mx, __shfl_xor(mx, 8, 64));
        float v0 = alpha * (mx - e0), v1 = alpha * (mx - e1);
        float v2 = alpha * (mx - e2), v3 = alpha * (mx - e3);
        float vm = fmaxf(fmaxf(v0, v1), fmaxf(v2, v3));
        vm = fmaxf(vm, __shfl_xor(vm, 1, 64));
        vm = fmaxf(vm, __shfl_xor(vm, 2, 64));
        vm = fmaxf(vm, __shfl_xor(vm, 4, 64));
        vm = fmaxf(vm, __shfl_xor(vm, 8, 64));
        float p0 = __expf(v0 - vm), p1 = __expf(v1 - vm);
        float p2 = __expf(v2 - vm), p3 = __expf(v3 - vm);
        float s = p0 + p1 + p2 + p3;
        s += __shfl_xor(s, 1, 64);
        s += __shfl_xor(s, 2, 64);
        s += __shfl_xor(s, 4, 64);
        s += __shfl_xor(s, 8, 64);
        const float sc = gam / s;            // fold gamma
        Ep[(4 * g + r) * 68 +  0 + r15] = p0 * sc;
        Ep[(4 * g + r) * 68 + 16 + r15] = p1 * sc;
        Ep[(4 * g + r) * 68 + 32 + r15] = p2 * sc;
        Ep[(4 * g + r) * 68 + 48 + r15] = p3 * sc;
    }
    asm volatile("s_waitcnt lgkmcnt(0)" ::: "memory");
    SBAR();
    frag_ab A0, A1;   // A layout: row r15 (channel), k = 8g+j / 32+8g+j
    {
        float4 q0 = *reinterpret_cast<const float4*>(&Ep[r15 * 68 + 8 * g]);
        float4 q1 = *reinterpret_cast<const float4*>(&Ep[r15 * 68 + 8 * g + 4]);
        float4 q2 = *reinterpret_cast<const float4*>(&Ep[r15 * 68 + 32 + 8 * g]);
        float4 q3 = *reinterpret_cast<const float4*>(&Ep[r15 * 68 + 32 + 8 * g + 4]);
        A0 = cvt2(q0, q1);
        A1 = cvt2(q2, q3);
    }
    SBAR();

    // ===== Phase 3: out = att @ M^T + x ; 64 grps of 64 cols, reg dbuf =====
    float* outS = Ep;   // reuse overlay (A-frags already in regs)
    float xvA[16], xvB[16];
    frag_ab B3A[4][2], B3B[4][2];

    auto ldxv = [&](int grp, float (&xv)[16]) {
#pragma unroll
        for (int r = 0; r < 16; ++r)
            xv[r] = x[(size_t)(row0 + r) * 4096 + grp * 64 + lane];
    };
    auto ldB3 = [&](int grp, frag_ab (&B)[4][2]) {
#pragma unroll
        for (int t = 0; t < 4; ++t)
#pragma unroll
            for (int h = 0; h < 2; ++h)
                B[t][h] = load_frag(MbfF + (((size_t)(4 * grp + t) * 2 + h) * 64 + lane) * 8);
    };

    ldxv(0, xvA); ldB3(0, B3A);
    ldxv(1, xvB); ldB3(1, B3B);
    SBAR();
#pragma unroll 1
    for (int i = 0; i < 32; ++i) {
        // ---- even grp e = 2i (xvA, B3A) ----
        if (i == 0) asm volatile("s_waitcnt vmcnt(24)" ::: "memory");
        else        asm volatile("s_waitcnt vmcnt(56)" ::: "memory");
        SBAR();
        {
            f32x4 d0 = {0.f, 0.f, 0.f, 0.f};
            f32x4 d1 = d0, d2 = d0, d3 = d0;
            d0 = MFMA16(A0, B3A[0][0], d0); d0 = MFMA16(A1, B3A[0][1], d0);
            d1 = MFMA16(A0, B3A[1][0], d1); d1 = MFMA16(A1, B3A[1][1], d1);
            d2 = MFMA16(A0, B3A[2][0], d2); d2 = MFMA16(A1, B3A[2][1], d2);
            d3 = MFMA16(A0, B3A[3][0], d3); d3 = MFMA16(A1, B3A[3][1], d3);
#pragma unroll
            for (int r = 0; r < 4; ++r) {
                outS[(4 * g + r) * 68 +  0 + r15] = d0[r];
                outS[(4 * g + r) * 68 + 16 + r15] = d1[r];
                outS[(4 * g + r) * 68 + 32 + r15] = d2[r];
                outS[(4 * g + r) * 68 + 48 + r15] = d3[r];
            }
            asm volatile("s_waitcnt lgkmcnt(0)" ::: "memory");
            SBAR();
            float sv[16];
#pragma unroll
            for (int r = 0; r < 16; ++r) sv[r] = outS[r * 68 + lane] + xvA[r];
            SBAR();
            if (i < 31) { ldxv(2 * i + 2, xvA); ldB3(2 * i + 2, B3A); }
            SBAR();
#pragma unroll
            for (int r = 0; r < 16; ++r)
                out[(size_t)(row0 + r) * 4096 + (2 * i) * 64 + lane] = sv[r];
        }
        SBAR();
        // ---- odd grp o = 2i+1 (xvB, B3B) ----
        if (i == 0)       asm volatile("s_waitcnt vmcnt(40)" ::: "memory");
        else if (i == 31) asm volatile("s_waitcnt vmcnt(32)" ::: "memory");
        else              asm volatile("s_waitcnt vmcnt(56)" ::: "memory");
        SBAR();
        {
            f32x4 d0 = {0.f, 0.f, 0.f, 0.f};
            f32x4 d1 = d0, d2 = d0, d3 = d0;
            d0 = MFMA16(A0, B3B[0][0], d0); d0 = MFMA16(A1, B3B[0][1], d0);
            d1 = MFMA16(A0, B3B[1][0], d1); d1 = MFMA16(A1, B3B[1][1], d1);
            d2 = MFMA16(A0, B3B[2][0], d2); d2 = MFMA16(A1, B3B[2][1], d2);
            d3 = MFMA16(A0, B3B[3][0], d3); d3 = MFMA16(A1, B3B[3][1], d3);
#pragma unroll
            for (int r = 0; r < 4; ++r) {
                outS[(4 * g + r) * 68 +  0 + r15] = d0[r];
                outS[(4 * g + r) * 68 + 16 + r15] = d1[r];
                outS[(4 * g + r) * 68 + 32 + r15] = d2[r];
                outS[(4 * g + r) * 68 + 48 + r15] = d3[r];
            }
            asm volatile("s_waitcnt lgkmcnt(0)" ::: "memory");
            SBAR();
            float sv[16];
#pragma unroll
            for (int r = 0; r < 16; ++r) sv[r] = outS[r * 68 + lane] + xvB[r];
            SBAR();
            if (i < 31) { ldxv(2 * i + 3, xvB); ldB3(2 * i + 3, B3B); }
            SBAR();
#pragma unroll
            for (int r = 0; r < 16; ++r)
                out[(size_t)(row0 + r) * 4096 + (2 * i + 1) * 64 + lane] = sv[r];
        }
        SBAR();
    }
}

extern "C" void kernel_launch(void* const* d_in, const int* in_sizes, int n_in,
                              void* d_out, int out_size, void* d_ws, size_t ws_size,
                              hipStream_t stream) {
    const float* x     = (const float*)d_in[0];
    const float* M     = (const float*)d_in[1];
    const float* aphal = (const float*)d_in[2];
    const float* gamma = (const float*)d_in[3];
    __hip_bfloat16* MtF  = (__hip_bfloat16*)d_ws;                  // 512 KB
    __hip_bfloat16* MbfF = (__hip_bfloat16*)d_ws + 64 * 4096;      // 512 KB

    hipLaunchKernelGGL(prep_frags, dim3(256), dim3(256), 0, stream, M, MtF, MbfF);
    hipLaunchKernelGGL(ccam_fused, dim3(1024), dim3(64), 0, stream,
                       x, MtF, MbfF, aphal, gamma, (float*)d_out);
}

// Round 10
// 172.837 us; speedup vs baseline: 1.1960x; 1.1724x over previous
//
#include <hip/hip_runtime.h>
#include <hip/hip_bf16.h>

// CCAM (fp32 in/out): x (16,1024,64,64), martx (4096,64).
// rows = B*C = 16384, N = 4096 spatial, KDIM = 64.
// energy[r][k] = sum_n x[r][n] * M[n][k]           (GEMM1, K=4096)
// att = softmax(alpha * (rowmax(energy) - energy))  (64-wide)
// out[r][n] = gamma * sum_k att[r][k]*M[n][k] + x[r][n]
//
// Round-10: SEQUENTIAL-STREAM experiment. Block = 8 rows; wave w owns row w.
//   stage:  wave w reads its 16 KB row fully sequentially (16 x 1KB float4
//           loads), cvt to bf16 into a 64 KB LDS x-image (stride 8208 B:
//           +4-bank row rotation -> conflict-free A-frag reads)
//   phase1: energy fully from LDS; wave = (kdim-tile t, K-half h); Ep (4 KB)
//   phase2: softmax; each lane directly builds its phase-3 A-frag slice
//   phase3: D + residual added IN PLACE into the LDS image (bf16); no
//           residual re-read from HBM at all
//   store:  wave w streams row w back out sequentially (16 x 1KB stores)
// HBM traffic = one dense read sweep + one dense write sweep per block.

using frag_ab = __attribute__((ext_vector_type(8))) short;   // 8 bf16
using f32x4   = __attribute__((ext_vector_type(4))) float;   // MFMA C/D

#define MFMA16(a, b, c) __builtin_amdgcn_mfma_f32_16x16x32_bf16((a), (b), (c), 0, 0, 0)

static __device__ __forceinline__ unsigned short f2bf_bits(float f) {
    __hip_bfloat16 h = __float2bfloat16(f);
    return *reinterpret_cast<const unsigned short*>(&h);
}
static __device__ __forceinline__ float bf2f(unsigned short u) {
    return __uint_as_float(((unsigned)u) << 16);
}
static __device__ __forceinline__ frag_ab load_frag(const __hip_bfloat16* p) {
    return *reinterpret_cast<const frag_ab*>(p);
}
static __device__ __forceinline__ frag_ab cvt2(float4 a, float4 b) {
    frag_ab r;
    r[0] = (short)f2bf_bits(a.x); r[1] = (short)f2bf_bits(a.y);
    r[2] = (short)f2bf_bits(a.z); r[3] = (short)f2bf_bits(a.w);
    r[4] = (short)f2bf_bits(b.x); r[5] = (short)f2bf_bits(b.y);
    r[6] = (short)f2bf_bits(b.z); r[7] = (short)f2bf_bits(b.w);
    return r;
}

// -------- kernel 0: build frag-linear B banks (unchanged, validated) --------
// MtF  (512 frags x 1 KB): frag f = slot*4+t, elem (lane,j) = M[32*slot+8g+j][16t+r15]
// MbfF (512 frags x 1 KB): frag f = nt*2+h,   elem (lane,j) = M[16nt+r15][32h+8g+j]
__global__ __launch_bounds__(256) void prep_frags(
        const float* __restrict__ M,
        __hip_bfloat16* __restrict__ MtF, __hip_bfloat16* __restrict__ MbfF) {
    const int w    = threadIdx.x >> 6;
    const int lane = threadIdx.x & 63;
    const int g    = lane >> 4;
    const int r15  = lane & 15;
    const int f    = blockIdx.x * 4 + w;    // 0..1023
    if (f < 512) {
        const int slot = f >> 2, t = f & 3;
        frag_ab fr;
#pragma unroll
        for (int j = 0; j < 8; ++j)
            fr[j] = (short)f2bf_bits(M[(size_t)(32 * slot + 8 * g + j) * 64 + 16 * t + r15]);
        *reinterpret_cast<frag_ab*>(MtF + ((size_t)f * 64 + lane) * 8) = fr;
    } else {
        const int f2 = f - 512;
        const float* src = M + (size_t)(16 * (f2 >> 1) + r15) * 64 + 32 * (f2 & 1) + 8 * g;
        float4 a = *reinterpret_cast<const float4*>(src);
        float4 b = *reinterpret_cast<const float4*>(src + 4);
        *reinterpret_cast<frag_ab*>(MbfF + ((size_t)f2 * 64 + lane) * 8) = cvt2(a, b);
    }
}

// -------- kernel 1: fused CCAM, 8-row blocks, sequential streams ------------
// LDS 69760 B: xB image 8 rows x 8208 B (bf16, stride 4104 elems) = 65664;
//              Ep[4][2][8][16] f32 = 4096 at offset 65664.
__global__ __launch_bounds__(512, 2) void ccam_fused(
        const float* __restrict__ x,
        const __hip_bfloat16* __restrict__ MtF,
        const __hip_bfloat16* __restrict__ MbfF,
        const float* __restrict__ aphal,
        const float* __restrict__ gamma,
        float* __restrict__ out) {
    __shared__ __align__(16) char smem[69760];
    float* Ep = (float*)(smem + 65664);    // [t][h][row][16] floats

    const int tid  = threadIdx.x;
    const int w    = tid >> 6;             // wave 0..7
    const int lane = tid & 63;
    const int g    = lane >> 4;
    const int r15  = lane & 15;
    const int r7   = r15 & 7;
    const int rowbase = blockIdx.x * 8;

    const float alpha = aphal[0];
    const float gam   = gamma[0];

    // ===== stage: wave w reads row w sequentially, bf16 into LDS =====
    {
        const float* xr = x + (size_t)(rowbase + w) * 4096;
        char* dst = smem + w * 8208;
#pragma unroll
        for (int rnd = 0; rnd < 2; ++rnd) {
            float4 v[8];
#pragma unroll
            for (int i = 0; i < 8; ++i)
                v[i] = *reinterpret_cast<const float4*>(xr + rnd * 2048 + i * 256 + 4 * lane);
#pragma unroll
            for (int i = 0; i < 8; ++i) {
                ushort4 u;
                u.x = f2bf_bits(v[i].x); u.y = f2bf_bits(v[i].y);
                u.z = f2bf_bits(v[i].z); u.w = f2bf_bits(v[i].w);
                *reinterpret_cast<ushort4*>(dst + (rnd * 2048 + i * 256 + 4 * lane) * 2) = u;
            }
        }
    }
    __syncthreads();

    // ===== phase 1: energy from LDS; wave = (kdim-tile t1, K-half h1) =====
    const int t1 = w >> 1;
    const int h1 = w & 1;
    f32x4 acc = {0.f, 0.f, 0.f, 0.f};
    {
        const char* arow = smem + r7 * 8208;
        frag_ab Bc = load_frag(MtF + (((size_t)(64 * h1) * 4 + t1) * 64 + lane) * 8);
#pragma unroll 4
        for (int s = 0; s < 64; ++s) {
            frag_ab Bn = Bc;
            if (s < 63)
                Bn = load_frag(MtF + (((size_t)(64 * h1 + s + 1) * 4 + t1) * 64 + lane) * 8);
            frag_ab A = *reinterpret_cast<const frag_ab*>(
                arow + (h1 * 2048 + 32 * s + 8 * g) * 2);
            acc = MFMA16(A, Bc, acc);
            Bc = Bn;
        }
    }
    // Ep: rows 0..7 live in lanes g<2 (D row = 4g+reg)
    if (g < 2) {
#pragma unroll
        for (int reg = 0; reg < 4; ++reg)
            Ep[(((t1 * 2 + h1) * 8) + 4 * g + reg) * 16 + r15] = acc[reg];
    }
    __syncthreads();

    // ===== phase 2: softmax; lane builds its own phase-3 A-frag slice =====
    // lane (g,r15): row r7; k = 8g+j (A0) and 32+8g+j (A1)
    float elo[8], ehi[8];
    {
        const int t0  = g >> 1;
        const int off = 8 * (g & 1);
        const float* e0 = Ep + ((t0 * 2 + 0) * 8 + r7) * 16 + off;
        const float* e1 = Ep + ((t0 * 2 + 1) * 8 + r7) * 16 + off;
        const float* e2 = Ep + (((t0 + 2) * 2 + 0) * 8 + r7) * 16 + off;
        const float* e3 = Ep + (((t0 + 2) * 2 + 1) * 8 + r7) * 16 + off;
        float4 a0 = *reinterpret_cast<const float4*>(e0);
        float4 a1 = *reinterpret_cast<const float4*>(e0 + 4);
        float4 b0 = *reinterpret_cast<const float4*>(e1);
        float4 b1 = *reinterpret_cast<const float4*>(e1 + 4);
        elo[0] = a0.x + b0.x; elo[1] = a0.y + b0.y; elo[2] = a0.z + b0.z; elo[3] = a0.w + b0.w;
        elo[4] = a1.x + b1.x; elo[5] = a1.y + b1.y; elo[6] = a1.z + b1.z; elo[7] = a1.w + b1.w;
        float4 c0 = *reinterpret_cast<const float4*>(e2);
        float4 c1 = *reinterpret_cast<const float4*>(e2 + 4);
        float4 d0 = *reinterpret_cast<const float4*>(e3);
        float4 d1 = *reinterpret_cast<const float4*>(e3 + 4);
        ehi[0] = c0.x + d0.x; ehi[1] = c0.y + d0.y; ehi[2] = c0.z + d0.z; ehi[3] = c0.w + d0.w;
        ehi[4] = c1.x + d1.x; ehi[5] = c1.y + d1.y; ehi[6] = c1.z + d1.z; ehi[7] = c1.w + d1.w;
    }
    float m = elo[0];
#pragma unroll
    for (int j = 1; j < 8; ++j) m = fmaxf(m, elo[j]);
#pragma unroll
    for (int j = 0; j < 8; ++j) m = fmaxf(m, ehi[j]);
    m = fmaxf(m, __shfl_xor(m, 8, 64));
    m = fmaxf(m, __shfl_xor(m, 16, 64));
    m = fmaxf(m, __shfl_xor(m, 32, 64));
#pragma unroll
    for (int j = 0; j < 8; ++j) { elo[j] = alpha * (m - elo[j]); ehi[j] = alpha * (m - ehi[j]); }
    float vm = elo[0];
#pragma unroll
    for (int j = 1; j < 8; ++j) vm = fmaxf(vm, elo[j]);
#pragma unroll
    for (int j = 0; j < 8; ++j) vm = fmaxf(vm, ehi[j]);
    vm = fmaxf(vm, __shfl_xor(vm, 8, 64));
    vm = fmaxf(vm, __shfl_xor(vm, 16, 64));
    vm = fmaxf(vm, __shfl_xor(vm, 32, 64));
    float s = 0.f;
#pragma unroll
    for (int j = 0; j < 8; ++j) { elo[j] = __expf(elo[j] - vm); s += elo[j]; }
#pragma unroll
    for (int j = 0; j < 8; ++j) { ehi[j] = __expf(ehi[j] - vm); s += ehi[j]; }
    s += __shfl_xor(s, 8, 64);
    s += __shfl_xor(s, 16, 64);
    s += __shfl_xor(s, 32, 64);
    const float sc = gam / s;               // fold gamma into attention
    frag_ab A0, A1;
#pragma unroll
    for (int j = 0; j < 8; ++j) {
        A0[j] = (short)f2bf_bits(elo[j] * sc);
        A1[j] = (short)f2bf_bits(ehi[j] * sc);
    }

    // ===== phase 3: out into LDS image in place; wave w owns cols [512w,+512) =====
#pragma unroll 1
    for (int gi = 0; gi < 8; ++gi) {
        const int grp = 8 * w + gi;
        frag_ab B[4][2];
#pragma unroll
        for (int t = 0; t < 4; ++t)
#pragma unroll
            for (int h = 0; h < 2; ++h)
                B[t][h] = load_frag(MbfF + (((size_t)(4 * grp + t) * 2 + h) * 64 + lane) * 8);
        f32x4 d0 = {0.f, 0.f, 0.f, 0.f};
        f32x4 d1 = d0, d2 = d0, d3 = d0;
        d0 = MFMA16(A0, B[0][0], d0); d0 = MFMA16(A1, B[0][1], d0);
        d1 = MFMA16(A0, B[1][0], d1); d1 = MFMA16(A1, B[1][1], d1);
        d2 = MFMA16(A0, B[2][0], d2); d2 = MFMA16(A1, B[2][1], d2);
        d3 = MFMA16(A0, B[3][0], d3); d3 = MFMA16(A1, B[3][1], d3);
        // D rows 0..7 live in lanes g<2 (row = 4g+reg); add residual in place
        if (g < 2) {
#pragma unroll
            for (int t = 0; t < 4; ++t) {
#pragma unroll
                for (int reg = 0; reg < 4; ++reg) {
                    const int row = 4 * g + reg;
                    const int col = grp * 64 + 16 * t + r15;
                    unsigned short* p = (unsigned short*)(smem + row * 8208) + col;
                    const float dv = (t == 0) ? d0[reg] : (t == 1) ? d1[reg]
                                   : (t == 2) ? d2[reg] : d3[reg];
                    *p = f2bf_bits(dv + bf2f(*p));
                }
            }
        }
    }
    __syncthreads();

    // ===== store: wave w streams row w out sequentially =====
    {
        const char* srow = smem + w * 8208;
        float* orow = out + (size_t)(rowbase + w) * 4096;
#pragma unroll
        for (int i = 0; i < 16; ++i) {
            const int col = 256 * i + 4 * lane;
            ushort4 u = *reinterpret_cast<const ushort4*>(srow + col * 2);
            float4 v;
            v.x = bf2f(u.x); v.y = bf2f(u.y); v.z = bf2f(u.z); v.w = bf2f(u.w);
            *reinterpret_cast<float4*>(orow + col) = v;
        }
    }
}

extern "C" void kernel_launch(void* const* d_in, const int* in_sizes, int n_in,
                              void* d_out, int out_size, void* d_ws, size_t ws_size,
                              hipStream_t stream) {
    const float* x     = (const float*)d_in[0];
    const float* M     = (const float*)d_in[1];
    const float* aphal = (const float*)d_in[2];
    const float* gamma = (const float*)d_in[3];
    __hip_bfloat16* MtF  = (__hip_bfloat16*)d_ws;                  // 512 KB
    __hip_bfloat16* MbfF = (__hip_bfloat16*)d_ws + 64 * 4096;      // 512 KB

    hipLaunchKernelGGL(prep_frags, dim3(256), dim3(256), 0, stream, M, MtF, MbfF);
    hipLaunchKernelGGL(ccam_fused, dim3(2048), dim3(512), 0, stream,
                       x, MtF, MbfF, aphal, gamma, (float*)d_out);
}